// Round 11
// baseline (820.290 us; speedup 1.0000x reference)
//
#include <hip/hip_runtime.h>
#include <stdint.h>

#define N_NODES 100000
#define N_EDGES 1600000
#define N_GRAPHS 128
#define DIN 100
#define DOUT 200
#define LDH 200   // f16 row stride for 200-dim buffers (400 B)
#define LDX 128   // f16 row stride for 100-dim layer (256 B = 4 lines, aligned)

#define NB 391       // buckets of 256 nodes (391*256 >= 100000)
#define BCAP 5120    // per-bucket capacity; E/NB=4092, sigma~64 -> +16 sigma margin
#define EPB 2048     // edges per block in bucketize (782 blocks, ~3/CU)

typedef unsigned short u16;
typedef unsigned int u32;
typedef _Float16 f16;
typedef f16 half8 __attribute__((ext_vector_type(8)));
typedef f16 half4 __attribute__((ext_vector_type(4)));
typedef f16 half2v __attribute__((ext_vector_type(2)));
typedef float floatx4 __attribute__((ext_vector_type(4)));

__device__ __forceinline__ float h2f(u16 h) {
  f16 x; __builtin_memcpy(&x, &h, 2); return (float)x;
}
__device__ __forceinline__ u16 f2h(float f) {
  f16 x = (f16)f; u16 r; __builtin_memcpy(&r, &x, 2); return r;
}

// ---------- pack W[K,200] (fp32) into MFMA B-frag order ----------
__device__ __forceinline__ void pack_frag(const float* __restrict__ W, int K, int nfrag,
                                          u16* __restrict__ out, int idx) {
  if (idx >= nfrag) return;
  int lane = idx & 63;
  int t = idx >> 6;
  int ct = t % 13, ks = t / 13;
  int n = ct * 16 + (lane & 15);
  int kbase = ks * 32 + (lane >> 4) * 8;
  u16 v[8];
  #pragma unroll
  for (int j = 0; j < 8; ++j) {
    int k = kbase + j;
    float f = (k < K && n < DOUT) ? W[(size_t)k * DOUT + n] : 0.f;
    v[j] = f2h(f);
  }
  uint4 o;
  o.x = (u32)v[0] | ((u32)v[1] << 16);
  o.y = (u32)v[2] | ((u32)v[3] << 16);
  o.z = (u32)v[4] | ((u32)v[5] << 16);
  o.w = (u32)v[6] | ((u32)v[7] << 16);
  *(uint4*)(out + (size_t)idx * 8) = o;
}

// ---------- fused prep: gbound | comb | pack1 | pack3 | init gcur ----------
// (no gstart/gend sentinel init here — racing with gbound band caused r9 NaN)
#define B_GB    391
#define B_COMB  549
#define B_PK1   562
#define B_PK3   585
#define B_TOT   587
__global__ void k_prep(const int* __restrict__ batch, int* __restrict__ gstart,
                       int* __restrict__ gend, int* __restrict__ gcur,
                       const float* __restrict__ Wc, const float* __restrict__ bc,
                       const float* __restrict__ W2, float* __restrict__ Wc2,
                       float* __restrict__ bc2, const float* __restrict__ W1,
                       const float* __restrict__ W3, u16* __restrict__ Wpk1,
                       u16* __restrict__ Wpk3) {
  int b = blockIdx.x, t = threadIdx.x;
  if (b < B_GB) {
    int i = b * 256 + t;
    if (i >= N_NODES) return;
    int g = batch[i];
    if (i == 0 || batch[i - 1] != g) gstart[g] = i;
    if (i == N_NODES - 1 || batch[i + 1] != g) gend[g] = i;
  } else if (b < B_COMB) {
    int gid = (b - B_GB) * 256 + t;
    if (gid >= 201 * DOUT) return;
    int r = gid / DOUT, c = gid % DOUT;
    const float* a = (r < DOUT) ? (Wc + (size_t)r * DOUT) : bc;
    float s = 0.f;
    for (int k = 0; k < DOUT; ++k) s += a[k] * W2[(size_t)k * DOUT + c];
    if (r < DOUT) Wc2[(size_t)r * DOUT + c] = s;
    else bc2[c] = s;
  } else if (b < B_PK1) {
    pack_frag(W1, DIN, 4 * 13 * 64, Wpk1, (b - B_COMB) * 256 + t);
  } else if (b < B_PK3) {
    pack_frag(W3, DOUT, 7 * 13 * 64, Wpk3, (b - B_PK1) * 256 + t);
  } else {
    int i = (b - B_PK3) * 256 + t;
    if (i < NB) gcur[i] = 0;
  }
}

// ---------- phase A: bucketize edges by dst>>8 ----------
__global__ void k_bucket(const int* __restrict__ src, const int* __restrict__ dst,
                         int* __restrict__ gcur, uint2* __restrict__ ebuf, int E) {
  __shared__ int hist[NB];
  __shared__ int base[NB];
  __shared__ int cur[NB];
  int t = threadIdx.x;
  int e0 = blockIdx.x * EPB;
  int e1 = min(e0 + EPB, E);
  for (int j = t; j < NB; j += 256) { hist[j] = 0; cur[j] = 0; }
  __syncthreads();
  for (int i = e0 + t; i < e1; i += 256)
    atomicAdd(&hist[dst[i] >> 8], 1);
  __syncthreads();
  for (int j = t; j < NB; j += 256)
    base[j] = hist[j] ? atomicAdd(&gcur[j], hist[j]) : 0;
  __syncthreads();
  for (int i = e0 + t; i < e1; i += 256) {
    int d = dst[i];
    int b = d >> 8;
    int off = atomicAdd(&cur[b], 1);
    int pos = base[b] + off;
    if (pos < BCAP)
      ebuf[(size_t)b * BCAP + pos] = make_uint2((u32)d, (u32)src[i]);
  }
}

// ---------- phase B: per-bucket (256 nodes) count+scan -> rowptr,dinv ; scatter -> col ----------
__global__ void k_csr(const uint2* __restrict__ ebuf, const int* __restrict__ gcur,
                      int* __restrict__ rowptr, float* __restrict__ dinv,
                      int* __restrict__ colv) {
  __shared__ int s_cnt[256];
  __shared__ int s_cur[256];
  __shared__ int s_scan[256];
  __shared__ int s_g[NB];
  __shared__ int s_base;
  int b = blockIdx.x, t = threadIdx.x;
  for (int j = t; j < NB; j += 256) s_g[j] = gcur[j];
  s_cnt[t] = 0;
  __syncthreads();
  if (t == 0) {
    int run = 0;
    for (int i = 0; i < b; ++i) run += s_g[i];
    s_base = run;
    if (b == NB - 1) rowptr[N_NODES] = run + s_g[b];  // == E
  }
  __syncthreads();
  int cnt = s_g[b];
  int base = s_base;
  int node0 = b << 8;
  const uint2* eb = ebuf + (size_t)b * BCAP;
  for (int i = t; i < cnt; i += 256)
    atomicAdd(&s_cnt[eb[i].x & 255], 1);
  __syncthreads();
  int v = s_cnt[t];
  s_scan[t] = v;
  __syncthreads();
  for (int o = 1; o < 256; o <<= 1) {
    int x = (t >= o) ? s_scan[t - o] : 0;
    __syncthreads();
    s_scan[t] += x;
    __syncthreads();
  }
  int run = s_scan[t] - v;  // exclusive
  s_cur[t] = base + run;
  int node = node0 + t;
  if (node < N_NODES) {
    rowptr[node] = base + run;
    dinv[node] = rsqrtf((float)v + 1.0f);
  }
  __syncthreads();
  for (int i = t; i < cnt; i += 256) {
    uint2 e = eb[i];
    int pos = atomicAdd(&s_cur[e.x & 255], 1);
    colv[pos] = (int)e.y;
  }
}

// ---------- fused post: xs = dinv * x -> f16 @LDX | pack2 ----------
#define P_XS  25000
#define P_TOT 25023
__global__ void k_post(const float* __restrict__ x, const float* __restrict__ dinv,
                       u16* __restrict__ xs, const float* __restrict__ Wc2,
                       u16* __restrict__ Wpk2) {
  int b = blockIdx.x, t = threadIdx.x;
  if (b < P_XS) {
    int gid = b * 256 + t;
    int node = gid >> 6, lane = gid & 63;
    if (node >= N_NODES) return;
    if (lane >= 50) {  // zero cols 100..127
      int c = 100 + (lane - 50) * 2;
      *(half2v*)(xs + (size_t)node * LDX + c) = half2v{0, 0};
      return;
    }
    float d = dinv[node];
    float2 vv = *(const float2*)(x + (size_t)node * DIN + lane * 2);
    half2v o; o[0] = (f16)(d * vv.x); o[1] = (f16)(d * vv.y);
    *(half2v*)(xs + (size_t)node * LDX + lane * 2) = o;
  } else {
    pack_frag(Wc2, DOUT, 7 * 13 * 64, Wpk2, (b - P_XS) * 256 + t);
  }
}

// ---------- MFMA GEMM: C = A @ Wpk (+bias)(+relu)(row-scale by dinv), 32 rows/wave ----------
template <int NKS>
__global__ __launch_bounds__(256) void k_gemm_mfma(const u16* __restrict__ A, int lda,
                                                   const u16* __restrict__ Wpk,
                                                   const float* __restrict__ bias,
                                                   const float* __restrict__ rowscale,
                                                   u16* __restrict__ C, int relu, int nrows) {
  int wv = threadIdx.x >> 6;
  int lane = threadIdx.x & 63;
  int r0 = blockIdx.x * 128 + wv * 32;
  int m = lane & 15, q = lane >> 4;
  int row0 = r0 + m, row1 = r0 + 16 + m;
  bool ok0 = (row0 < nrows), ok1 = (row1 < nrows);
  const u16* a0p = A + (size_t)row0 * lda + q * 8;
  const u16* a1p = A + (size_t)row1 * lda + q * 8;

  floatx4 acc0[13], acc1[13];
  #pragma unroll
  for (int ct = 0; ct < 13; ++ct) {
    acc0[ct] = floatx4{0.f, 0.f, 0.f, 0.f};
    acc1[ct] = floatx4{0.f, 0.f, 0.f, 0.f};
  }

  const u16* wp = Wpk + (size_t)lane * 8;
  #pragma unroll
  for (int ks = 0; ks < NKS; ++ks) {
    half8 a0 = ok0 ? *(const half8*)(a0p + ks * 32) : half8{0, 0, 0, 0, 0, 0, 0, 0};
    half8 a1 = ok1 ? *(const half8*)(a1p + ks * 32) : half8{0, 0, 0, 0, 0, 0, 0, 0};
    #pragma unroll
    for (int ct = 0; ct < 13; ++ct) {
      half8 bfr = *(const half8*)(wp + (size_t)(ks * 13 + ct) * 512);
      acc0[ct] = __builtin_amdgcn_mfma_f32_16x16x32_f16(a0, bfr, acc0[ct], 0, 0, 0);
      acc1[ct] = __builtin_amdgcn_mfma_f32_16x16x32_f16(a1, bfr, acc1[ct], 0, 0, 0);
    }
  }

  float sc0[4], sc1[4];
  #pragma unroll
  for (int rg = 0; rg < 4; ++rg) {
    int or0 = r0 + q * 4 + rg;
    int or1 = r0 + 16 + q * 4 + rg;
    sc0[rg] = (rowscale && or0 < nrows) ? rowscale[or0] : 1.f;
    sc1[rg] = (rowscale && or1 < nrows) ? rowscale[or1] : 1.f;
  }

  #pragma unroll
  for (int ct = 0; ct < 13; ++ct) {
    int c = ct * 16 + m;
    if (c >= DOUT) continue;
    float bv = bias ? bias[c] : 0.f;
    #pragma unroll
    for (int rg = 0; rg < 4; ++rg) {
      int or0 = r0 + q * 4 + rg;
      if (or0 < nrows) {
        float v = acc0[ct][rg] + bv;
        if (relu) v = fmaxf(v, 0.f);
        C[(size_t)or0 * LDH + c] = f2h(v * sc0[rg]);
      }
      int or1 = r0 + 16 + q * 4 + rg;
      if (or1 < nrows) {
        float v = acc1[ct][rg] + bv;
        if (relu) v = fmaxf(v, 0.f);
        C[(size_t)or1 * LDH + c] = f2h(v * sc1[rg]);
      }
    }
  }
}

// ---------- aggregation D=200, XCD-split column halves ----------
// block b: half = (b>>2)&1, node group = ((b>>3)<<2)|(b&3); 4 waves = 4 nodes.
// With round-robin blockIdx->XCD, each XCD touches only one 200B half per row.
__global__ void k_agg200h(const u16* __restrict__ T, const float* __restrict__ dinv,
                          const int* __restrict__ rowptr, const int* __restrict__ col,
                          const float* __restrict__ bias, u16* __restrict__ OUT,
                          int relu) {
  int b = blockIdx.x;
  int half = (b >> 2) & 1;
  int ng = ((b >> 3) << 2) | (b & 3);
  int node = ng * 4 + (threadIdx.x >> 6);
  int lane = threadIdx.x & 63;
  if (node >= N_NODES || lane >= 50) return;
  int c2 = half * 100 + lane * 2;
  float ax = 0.f, ay = 0.f;
  int beg = rowptr[node], end = rowptr[node + 1];
  int e = beg;
  for (; e + 8 <= end; e += 8) {
    int s[8];
    half2v tv[8];
    #pragma unroll
    for (int j = 0; j < 8; ++j) s[j] = col[e + j];
    #pragma unroll
    for (int j = 0; j < 8; ++j)
      tv[j] = *(const half2v*)(T + (size_t)s[j] * LDH + c2);
    #pragma unroll
    for (int j = 0; j < 8; ++j) {
      ax += (float)tv[j][0];
      ay += (float)tv[j][1];
    }
  }
  for (; e < end; ++e) {
    half2v tv = *(const half2v*)(T + (size_t)col[e] * LDH + c2);
    ax += (float)tv[0]; ay += (float)tv[1];
  }
  float di = dinv[node];
  half2v sv = *(const half2v*)(T + (size_t)node * LDH + c2);
  float rx = di * (ax + (float)sv[0]);
  float ry = di * (ay + (float)sv[1]);
  if (bias) { rx += bias[c2 + 0]; ry += bias[c2 + 1]; }
  if (relu) { rx = fmaxf(rx, 0.f); ry = fmaxf(ry, 0.f); }
  half2v o;
  o[0] = (f16)rx; o[1] = (f16)ry;
  *(half2v*)(OUT + (size_t)node * LDH + c2) = o;
}

// ---------- aggregation D=100 (LDX=128), XCD-split at the 64-col line boundary ----------
// half footprint = exactly 2 aligned 64B lines; 64 lanes x u16.
// xs cols 100..127 are zero, so half-1 lanes >= 36 just aggregate zeros.
__global__ void k_agg100h(const u16* __restrict__ T, const float* __restrict__ dinv,
                          const int* __restrict__ rowptr, const int* __restrict__ col,
                          u16* __restrict__ OUT) {
  int b = blockIdx.x;
  int half = (b >> 2) & 1;
  int ng = ((b >> 3) << 2) | (b & 3);
  int node = ng * 4 + (threadIdx.x >> 6);
  int lane = threadIdx.x & 63;
  if (node >= N_NODES) return;
  int c = half * 64 + lane;
  float ax = 0.f;
  int beg = rowptr[node], end = rowptr[node + 1];
  int e = beg;
  for (; e + 8 <= end; e += 8) {
    int s[8];
    u16 tv[8];
    #pragma unroll
    for (int j = 0; j < 8; ++j) s[j] = col[e + j];
    #pragma unroll
    for (int j = 0; j < 8; ++j)
      tv[j] = T[(size_t)s[j] * LDX + c];
    #pragma unroll
    for (int j = 0; j < 8; ++j) ax += h2f(tv[j]);
  }
  for (; e < end; ++e) ax += h2f(T[(size_t)col[e] * LDX + c]);
  float di = dinv[node];
  float sv = h2f(T[(size_t)node * LDX + c]);
  OUT[(size_t)node * LDX + c] = f2h(di * (ax + sv));
}

// ---------- pooling ----------
#define POOL_CHUNKS 8
__global__ void k_pool1h(const u16* __restrict__ H, const int* __restrict__ gstart,
                         const int* __restrict__ gend, float* __restrict__ part) {
  int g = blockIdx.x, c = blockIdx.y, t = threadIdx.x;
  if (t >= DOUT) return;
  int s = gstart[g], e = gend[g];
  float m = -3.4e38f;
  if (s >= 0 && e >= s && e < N_NODES) {  // poison-safe (0xAA.. is negative)
    int len = e - s + 1;
    int cs = s + (int)(((long long)len * c) / POOL_CHUNKS);
    int ce = s + (int)(((long long)len * (c + 1)) / POOL_CHUNKS);
    for (int i = cs; i < ce; ++i) m = fmaxf(m, h2f(H[(size_t)i * LDH + t]));
  }
  part[(size_t)(g * POOL_CHUNKS + c) * DOUT + t] = m;
}

__global__ void k_poolcls(const float* __restrict__ part, const float* __restrict__ Wcls,
                          const float* __restrict__ bcls, float* __restrict__ out) {
  __shared__ float l0s[256], l1s[256];
  int g = blockIdx.x, t = threadIdx.x;
  float c0 = 0.f, c1 = 0.f;
  if (t < DOUT) {
    float m = -3.4e38f;
    #pragma unroll
    for (int c = 0; c < POOL_CHUNKS; ++c)
      m = fmaxf(m, part[(size_t)(g * POOL_CHUNKS + c) * DOUT + t]);
    c0 = m * Wcls[t * 2 + 0];
    c1 = m * Wcls[t * 2 + 1];
  }
  l0s[t] = c0; l1s[t] = c1;
  __syncthreads();
  for (int o = 128; o > 0; o >>= 1) {
    if (t < o) { l0s[t] += l0s[t + o]; l1s[t] += l1s[t + o]; }
    __syncthreads();
  }
  if (t == 0) {
    float l0 = l0s[0] + bcls[0], l1 = l1s[0] + bcls[1];
    float m = fmaxf(l0, l1);
    float e0 = expf(l0 - m), e1 = expf(l1 - m);
    float inv = 1.0f / (e0 + e1);
    out[g * 2 + 0] = e0 * inv;
    out[g * 2 + 1] = e1 * inv;
  }
}

static inline size_t align256(size_t x) { return (x + 255) & ~(size_t)255; }

extern "C" void kernel_launch(void* const* d_in, const int* in_sizes, int n_in,
                              void* d_out, int out_size, void* d_ws, size_t ws_size,
                              hipStream_t stream) {
  const float* x     = (const float*)d_in[0];
  const int*   ei    = (const int*)d_in[1];
  const int*   batch = (const int*)d_in[2];
  const float* W1    = (const float*)d_in[3];
  const float* b1    = (const float*)d_in[4];
  const float* Wc    = (const float*)d_in[5];
  const float* bc    = (const float*)d_in[6];
  const float* W2    = (const float*)d_in[7];
  const float* b2    = (const float*)d_in[8];
  const float* W3    = (const float*)d_in[9];
  const float* b3    = (const float*)d_in[10];
  const float* Wcls  = (const float*)d_in[11];
  const float* bcls  = (const float*)d_in[12];
  float* out = (float*)d_out;

  const int N = N_NODES, E = N_EDGES;
  const int* src = ei;
  const int* dst = ei + E;

  char* ws = (char*)d_ws;
  size_t off = 0;
  float* dinv   = (float*)(ws + off); off = align256(off + (size_t)N * 4);
  int*   rowptr = (int*)  (ws + off); off = align256(off + (size_t)(N + 1) * 4);
  int*   col    = (int*)  (ws + off); off = align256(off + (size_t)E * 4);
  int*   gcur   = (int*)  (ws + off); off = align256(off + (size_t)NB * 4);
  int*   gstart = (int*)  (ws + off); off = align256(off + 512);
  int*   gend   = (int*)  (ws + off); off = align256(off + 512);
  float* Wc2    = (float*)(ws + off); off = align256(off + (size_t)DOUT * DOUT * 4);
  float* bc2    = (float*)(ws + off); off = align256(off + (size_t)DOUT * 4);
  u16*   Wpk1   = (u16*)  (ws + off); off = align256(off + (size_t)4 * 13 * 64 * 8 * 2);
  u16*   Wpk2   = (u16*)  (ws + off); off = align256(off + (size_t)7 * 13 * 64 * 8 * 2);
  u16*   Wpk3   = (u16*)  (ws + off); off = align256(off + (size_t)7 * 13 * 64 * 8 * 2);
  u16*   xs     = (u16*)  (ws + off); off = align256(off + ((size_t)N * LDX + 128) * 2);
  u16*   bufX   = (u16*)  (ws + off); off = align256(off + ((size_t)N * LDX + 128) * 2);
  u16*   buf0   = (u16*)  (ws + off); off = align256(off + ((size_t)N * LDH + 128) * 2);
  u16*   buf1   = (u16*)  (ws + off); off = align256(off + ((size_t)N * LDH + 128) * 2);
  u16*   buf2   = (u16*)  (ws + off); off = align256(off + ((size_t)N * LDH + 128) * 2);

  uint2* ebuf = (uint2*)buf0;   // 16.0 MB bucket scratch aliases buf0 (dead before GEMM1 out)
  float* part = (float*)buf1;   // pooling partials alias buf1 (dead at pool time)

  // 1) prep: graph bounds, Wc@W2 fold, pack W1/W3, init cursors
  k_prep<<<B_TOT, 256, 0, stream>>>(batch, gstart, gend, gcur,
                                    Wc, bc, W2, Wc2, bc2, W1, W3, Wpk1, Wpk3);
  // 2) bucketize edges by dst (391 buckets of 256 nodes)
  k_bucket<<<(E + EPB - 1) / EPB, 256, 0, stream>>>(src, dst, gcur, ebuf, E);
  // 3) per-bucket CSR build -> rowptr, dinv, col
  k_csr<<<NB, 256, 0, stream>>>(ebuf, gcur, rowptr, dinv, col);
  // 4) post: xs = dinv*x (f16 @LDX) + pack Wc2
  k_post<<<P_TOT, 256, 0, stream>>>(x, dinv, xs, Wc2, Wpk2);

  int gemmb = (N + 127) / 128;
  int aggb  = 2 * (((N + 3) / 4 + 3) / 4) * 4;  // 2 halves x 25000 groups, supergroups of 8
  aggb = 50000;

  // layer 1: agg(xs) -> GEMM W1 (+b1, relu), unscaled H1
  k_agg100h<<<aggb, 256, 0, stream>>>(xs, dinv, rowptr, col, bufX);
  k_gemm_mfma<4><<<gemmb, 256, 0, stream>>>(bufX, LDX, Wpk1, b1, nullptr, buf0, 1, N);
  // T2s = dinv .* (H1 @ (Wc@W2) + bc@W2)
  k_gemm_mfma<7><<<gemmb, 256, 0, stream>>>(buf0, LDH, Wpk2, bc2, dinv, buf2, 0, N);
  // h2 = relu(di*(sum T2s + T2s_self) + b2)
  k_agg200h<<<aggb, 256, 0, stream>>>(buf2, dinv, rowptr, col, b2, buf0, 1);
  // T3s = dinv .* (h2 @ W3)
  k_gemm_mfma<7><<<gemmb, 256, 0, stream>>>(buf0, LDH, Wpk3, nullptr, dinv, buf1, 0, N);
  // h3 = di*(sum T3s + T3s_self) + b3
  k_agg200h<<<aggb, 256, 0, stream>>>(buf1, dinv, rowptr, col, b3, buf2, 0);

  // pool + fused classifier/softmax
  dim3 pg(N_GRAPHS, POOL_CHUNKS);
  k_pool1h<<<pg, 256, 0, stream>>>(buf2, gstart, gend, part);
  k_poolcls<<<N_GRAPHS, 256, 0, stream>>>(part, Wcls, bcls, out);
}

// Round 12
// 680.592 us; speedup vs baseline: 1.2053x; 1.2053x over previous
//
#include <hip/hip_runtime.h>
#include <stdint.h>

#define N_NODES 100000
#define N_EDGES 1600000
#define N_GRAPHS 128
#define DIN 100
#define DOUT 200
#define LDH 200   // f16 row stride for 200-dim buffers (400 B)
#define LDX 128   // f16 row stride for 100-dim layer (256 B = 4 lines, aligned)

#define NB 391       // buckets of 256 nodes (391*256 >= 100000)
#define BCAP 5120    // per-bucket capacity; E/NB=4092, sigma~64 -> +16 sigma margin
#define EPB 2048     // edges per block in bucketize (782 blocks, ~3/CU)

typedef unsigned short u16;
typedef unsigned int u32;
typedef _Float16 f16;
typedef f16 half8 __attribute__((ext_vector_type(8)));
typedef f16 half4 __attribute__((ext_vector_type(4)));
typedef f16 half2v __attribute__((ext_vector_type(2)));
typedef float floatx4 __attribute__((ext_vector_type(4)));

__device__ __forceinline__ float h2f(u16 h) {
  f16 x; __builtin_memcpy(&x, &h, 2); return (float)x;
}
__device__ __forceinline__ u16 f2h(float f) {
  f16 x = (f16)f; u16 r; __builtin_memcpy(&r, &x, 2); return r;
}

// ---------- pack W[K,200] (fp32) into MFMA B-frag order ----------
// frag(ks, ct, lane, j) = f16( W[k][n] ), n = ct*16 + (lane&15), k = ks*32 + (lane>>4)*8 + j
__device__ __forceinline__ void pack_frag(const float* __restrict__ W, int K, int nfrag,
                                          u16* __restrict__ out, int idx) {
  if (idx >= nfrag) return;
  int lane = idx & 63;
  int t = idx >> 6;
  int ct = t % 13, ks = t / 13;
  int n = ct * 16 + (lane & 15);
  int kbase = ks * 32 + (lane >> 4) * 8;
  u16 v[8];
  #pragma unroll
  for (int j = 0; j < 8; ++j) {
    int k = kbase + j;
    float f = (k < K && n < DOUT) ? W[(size_t)k * DOUT + n] : 0.f;
    v[j] = f2h(f);
  }
  uint4 o;
  o.x = (u32)v[0] | ((u32)v[1] << 16);
  o.y = (u32)v[2] | ((u32)v[3] << 16);
  o.z = (u32)v[4] | ((u32)v[5] << 16);
  o.w = (u32)v[6] | ((u32)v[7] << 16);
  *(uint4*)(out + (size_t)idx * 8) = o;
}

// ---------- fused prep: gbound | comb | pack1 | pack3 | init gcur ----------
// NOTE: NO sentinel init of gstart/gend here — that raced with the gbound band
// (blocks in one launch are unordered) and caused round-9's NaN. Empty graphs
// are caught by k_pool1h's poison guard (0xAA.. is negative).
#define B_GB    391
#define B_COMB  549
#define B_PK1   562
#define B_PK3   585
#define B_TOT   587
__global__ void k_prep(const int* __restrict__ batch, int* __restrict__ gstart,
                       int* __restrict__ gend, int* __restrict__ gcur,
                       const float* __restrict__ Wc, const float* __restrict__ bc,
                       const float* __restrict__ W2, float* __restrict__ Wc2,
                       float* __restrict__ bc2, const float* __restrict__ W1,
                       const float* __restrict__ W3, u16* __restrict__ Wpk1,
                       u16* __restrict__ Wpk3) {
  int b = blockIdx.x, t = threadIdx.x;
  if (b < B_GB) {
    int i = b * 256 + t;
    if (i >= N_NODES) return;
    int g = batch[i];
    if (i == 0 || batch[i - 1] != g) gstart[g] = i;
    if (i == N_NODES - 1 || batch[i + 1] != g) gend[g] = i;
  } else if (b < B_COMB) {
    int gid = (b - B_GB) * 256 + t;
    if (gid >= 201 * DOUT) return;
    int r = gid / DOUT, c = gid % DOUT;
    const float* a = (r < DOUT) ? (Wc + (size_t)r * DOUT) : bc;
    float s = 0.f;
    for (int k = 0; k < DOUT; ++k) s += a[k] * W2[(size_t)k * DOUT + c];
    if (r < DOUT) Wc2[(size_t)r * DOUT + c] = s;
    else bc2[c] = s;
  } else if (b < B_PK1) {
    pack_frag(W1, DIN, 4 * 13 * 64, Wpk1, (b - B_COMB) * 256 + t);
  } else if (b < B_PK3) {
    pack_frag(W3, DOUT, 7 * 13 * 64, Wpk3, (b - B_PK1) * 256 + t);
  } else {
    int i = (b - B_PK3) * 256 + t;
    if (i < NB) gcur[i] = 0;
  }
}

// ---------- phase A: bucketize edges by dst>>8 ----------
__global__ void k_bucket(const int* __restrict__ src, const int* __restrict__ dst,
                         int* __restrict__ gcur, uint2* __restrict__ ebuf, int E) {
  __shared__ int hist[NB];
  __shared__ int base[NB];
  __shared__ int cur[NB];
  int t = threadIdx.x;
  int e0 = blockIdx.x * EPB;
  int e1 = min(e0 + EPB, E);
  for (int j = t; j < NB; j += 256) { hist[j] = 0; cur[j] = 0; }
  __syncthreads();
  for (int i = e0 + t; i < e1; i += 256)
    atomicAdd(&hist[dst[i] >> 8], 1);
  __syncthreads();
  for (int j = t; j < NB; j += 256)
    base[j] = hist[j] ? atomicAdd(&gcur[j], hist[j]) : 0;
  __syncthreads();
  for (int i = e0 + t; i < e1; i += 256) {
    int d = dst[i];
    int b = d >> 8;
    int off = atomicAdd(&cur[b], 1);
    int pos = base[b] + off;
    if (pos < BCAP)
      ebuf[(size_t)b * BCAP + pos] = make_uint2((u32)d, (u32)src[i]);
  }
}

// ---------- phase B: per-bucket (256 nodes) count+scan -> rowptr,dinv ; scatter -> col ----------
__global__ void k_csr(const uint2* __restrict__ ebuf, const int* __restrict__ gcur,
                      int* __restrict__ rowptr, float* __restrict__ dinv,
                      int* __restrict__ colv) {
  __shared__ int s_cnt[256];
  __shared__ int s_cur[256];
  __shared__ int s_scan[256];
  __shared__ int s_g[NB];
  __shared__ int s_base;
  int b = blockIdx.x, t = threadIdx.x;
  for (int j = t; j < NB; j += 256) s_g[j] = gcur[j];
  s_cnt[t] = 0;
  __syncthreads();
  if (t == 0) {
    int run = 0;
    for (int i = 0; i < b; ++i) run += s_g[i];
    s_base = run;
    if (b == NB - 1) rowptr[N_NODES] = run + s_g[b];  // == E
  }
  __syncthreads();
  int cnt = s_g[b];
  int base = s_base;
  int node0 = b << 8;
  const uint2* eb = ebuf + (size_t)b * BCAP;
  for (int i = t; i < cnt; i += 256)
    atomicAdd(&s_cnt[eb[i].x & 255], 1);
  __syncthreads();
  int v = s_cnt[t];
  s_scan[t] = v;
  __syncthreads();
  for (int o = 1; o < 256; o <<= 1) {
    int x = (t >= o) ? s_scan[t - o] : 0;
    __syncthreads();
    s_scan[t] += x;
    __syncthreads();
  }
  int run = s_scan[t] - v;  // exclusive
  s_cur[t] = base + run;
  int node = node0 + t;
  if (node < N_NODES) {
    rowptr[node] = base + run;
    dinv[node] = rsqrtf((float)v + 1.0f);
  }
  __syncthreads();
  for (int i = t; i < cnt; i += 256) {
    uint2 e = eb[i];
    int pos = atomicAdd(&s_cur[e.x & 255], 1);
    colv[pos] = (int)e.y;
  }
}

// ---------- fused post: xs = dinv * x -> f16 @LDX | pack2 ----------
#define P_XS  25000
#define P_TOT 25023
__global__ void k_post(const float* __restrict__ x, const float* __restrict__ dinv,
                       u16* __restrict__ xs, const float* __restrict__ Wc2,
                       u16* __restrict__ Wpk2) {
  int b = blockIdx.x, t = threadIdx.x;
  if (b < P_XS) {
    int gid = b * 256 + t;
    int node = gid >> 6, lane = gid & 63;
    if (node >= N_NODES) return;
    if (lane >= 50) {  // zero cols 100..127 (14 lanes x 2)
      int c = 100 + (lane - 50) * 2;
      *(half2v*)(xs + (size_t)node * LDX + c) = half2v{0, 0};
      return;
    }
    float d = dinv[node];
    float2 vv = *(const float2*)(x + (size_t)node * DIN + lane * 2);
    half2v o; o[0] = (f16)(d * vv.x); o[1] = (f16)(d * vv.y);
    *(half2v*)(xs + (size_t)node * LDX + lane * 2) = o;
  } else {
    pack_frag(Wc2, DOUT, 7 * 13 * 64, Wpk2, (b - P_XS) * 256 + t);
  }
}

// ---------- MFMA GEMM: C = A @ Wpk (+bias)(+relu)(row-scale by dinv), 32 rows/wave ----------
template <int NKS>
__global__ __launch_bounds__(256) void k_gemm_mfma(const u16* __restrict__ A, int lda,
                                                   const u16* __restrict__ Wpk,
                                                   const float* __restrict__ bias,
                                                   const float* __restrict__ rowscale,
                                                   u16* __restrict__ C, int relu, int nrows) {
  int wv = threadIdx.x >> 6;
  int lane = threadIdx.x & 63;
  int r0 = blockIdx.x * 128 + wv * 32;
  int m = lane & 15, q = lane >> 4;
  int row0 = r0 + m, row1 = r0 + 16 + m;
  bool ok0 = (row0 < nrows), ok1 = (row1 < nrows);
  const u16* a0p = A + (size_t)row0 * lda + q * 8;
  const u16* a1p = A + (size_t)row1 * lda + q * 8;

  floatx4 acc0[13], acc1[13];
  #pragma unroll
  for (int ct = 0; ct < 13; ++ct) {
    acc0[ct] = floatx4{0.f, 0.f, 0.f, 0.f};
    acc1[ct] = floatx4{0.f, 0.f, 0.f, 0.f};
  }

  const u16* wp = Wpk + (size_t)lane * 8;
  #pragma unroll
  for (int ks = 0; ks < NKS; ++ks) {
    half8 a0 = ok0 ? *(const half8*)(a0p + ks * 32) : half8{0, 0, 0, 0, 0, 0, 0, 0};
    half8 a1 = ok1 ? *(const half8*)(a1p + ks * 32) : half8{0, 0, 0, 0, 0, 0, 0, 0};
    #pragma unroll
    for (int ct = 0; ct < 13; ++ct) {
      half8 bfr = *(const half8*)(wp + (size_t)(ks * 13 + ct) * 512);
      acc0[ct] = __builtin_amdgcn_mfma_f32_16x16x32_f16(a0, bfr, acc0[ct], 0, 0, 0);
      acc1[ct] = __builtin_amdgcn_mfma_f32_16x16x32_f16(a1, bfr, acc1[ct], 0, 0, 0);
    }
  }

  float sc0[4], sc1[4];
  #pragma unroll
  for (int rg = 0; rg < 4; ++rg) {
    int or0 = r0 + q * 4 + rg;
    int or1 = r0 + 16 + q * 4 + rg;
    sc0[rg] = (rowscale && or0 < nrows) ? rowscale[or0] : 1.f;
    sc1[rg] = (rowscale && or1 < nrows) ? rowscale[or1] : 1.f;
  }

  // C/D layout: col = ct*16 + m, row = base + q*4 + reg
  #pragma unroll
  for (int ct = 0; ct < 13; ++ct) {
    int c = ct * 16 + m;
    if (c >= DOUT) continue;
    float bv = bias ? bias[c] : 0.f;
    #pragma unroll
    for (int rg = 0; rg < 4; ++rg) {
      int or0 = r0 + q * 4 + rg;
      if (or0 < nrows) {
        float v = acc0[ct][rg] + bv;
        if (relu) v = fmaxf(v, 0.f);
        C[(size_t)or0 * LDH + c] = f2h(v * sc0[rg]);
      }
      int or1 = r0 + 16 + q * 4 + rg;
      if (or1 < nrows) {
        float v = acc1[ct][rg] + bv;
        if (relu) v = fmaxf(v, 0.f);
        C[(size_t)or1 * LDH + c] = f2h(v * sc1[rg]);
      }
    }
  }
}

// ---------- aggregation D=200, pre-scaled rows: out = relu?(di*(sum Ts[col] + Ts[i]) + b) ----------
__global__ void k_agg200h(const u16* __restrict__ T, const float* __restrict__ dinv,
                          const int* __restrict__ rowptr, const int* __restrict__ col,
                          const float* __restrict__ bias, u16* __restrict__ OUT,
                          int relu) {
  int wave = (blockIdx.x * blockDim.x + threadIdx.x) >> 6;
  int lane = threadIdx.x & 63;
  if (wave >= N_NODES || lane >= 50) return;
  int node = wave;
  int c4 = lane * 4;
  float ax = 0.f, ay = 0.f, az = 0.f, aw = 0.f;
  int beg = rowptr[node], end = rowptr[node + 1];
  int e = beg;
  for (; e + 8 <= end; e += 8) {
    int s[8];
    half4 tv[8];
    #pragma unroll
    for (int j = 0; j < 8; ++j) s[j] = col[e + j];
    #pragma unroll
    for (int j = 0; j < 8; ++j)
      tv[j] = *(const half4*)(T + (size_t)s[j] * LDH + c4);
    #pragma unroll
    for (int j = 0; j < 8; ++j) {
      ax += (float)tv[j][0];
      ay += (float)tv[j][1];
      az += (float)tv[j][2];
      aw += (float)tv[j][3];
    }
  }
  for (; e < end; ++e) {
    half4 tv = *(const half4*)(T + (size_t)col[e] * LDH + c4);
    ax += (float)tv[0]; ay += (float)tv[1];
    az += (float)tv[2]; aw += (float)tv[3];
  }
  float di = dinv[node];
  half4 sv = *(const half4*)(T + (size_t)node * LDH + c4);
  float rx = di * (ax + (float)sv[0]);
  float ry = di * (ay + (float)sv[1]);
  float rz = di * (az + (float)sv[2]);
  float rw = di * (aw + (float)sv[3]);
  if (bias) {
    rx += bias[c4 + 0]; ry += bias[c4 + 1];
    rz += bias[c4 + 2]; rw += bias[c4 + 3];
  }
  if (relu) {
    rx = fmaxf(rx, 0.f); ry = fmaxf(ry, 0.f);
    rz = fmaxf(rz, 0.f); rw = fmaxf(rw, 0.f);
  }
  half4 o;
  o[0] = (f16)rx; o[1] = (f16)ry; o[2] = (f16)rz; o[3] = (f16)rw;
  *(half4*)(OUT + (size_t)node * LDH + c4) = o;
}

// ---------- aggregation D=100 on pre-scaled xs (LDX aligned), out @LDX ----------
__global__ void k_agg100h(const u16* __restrict__ T, const float* __restrict__ dinv,
                          const int* __restrict__ rowptr, const int* __restrict__ col,
                          u16* __restrict__ OUT) {
  int wave = (blockIdx.x * blockDim.x + threadIdx.x) >> 6;
  int lane = threadIdx.x & 63;
  if (wave >= N_NODES) return;
  int node = wave;
  if (lane >= 50) {
    int c = 100 + (lane - 50) * 2;
    *(half2v*)(OUT + (size_t)node * LDX + c) = half2v{0, 0};
    return;
  }
  int c2 = lane * 2;
  float ax = 0.f, ay = 0.f;
  int beg = rowptr[node], end = rowptr[node + 1];
  int e = beg;
  for (; e + 8 <= end; e += 8) {
    int s[8];
    half2v tv[8];
    #pragma unroll
    for (int j = 0; j < 8; ++j) s[j] = col[e + j];
    #pragma unroll
    for (int j = 0; j < 8; ++j)
      tv[j] = *(const half2v*)(T + (size_t)s[j] * LDX + c2);
    #pragma unroll
    for (int j = 0; j < 8; ++j) {
      ax += (float)tv[j][0];
      ay += (float)tv[j][1];
    }
  }
  for (; e < end; ++e) {
    half2v tv = *(const half2v*)(T + (size_t)col[e] * LDX + c2);
    ax += (float)tv[0]; ay += (float)tv[1];
  }
  float di = dinv[node];
  half2v sv = *(const half2v*)(T + (size_t)node * LDX + c2);
  half2v o;
  o[0] = (f16)(di * (ax + (float)sv[0]));
  o[1] = (f16)(di * (ay + (float)sv[1]));
  *(half2v*)(OUT + (size_t)node * LDX + c2) = o;
}

// ---------- pooling ----------
#define POOL_CHUNKS 8
__global__ void k_pool1h(const u16* __restrict__ H, const int* __restrict__ gstart,
                         const int* __restrict__ gend, float* __restrict__ part) {
  int g = blockIdx.x, c = blockIdx.y, t = threadIdx.x;
  if (t >= DOUT) return;
  int s = gstart[g], e = gend[g];
  float m = -3.4e38f;
  if (s >= 0 && e >= s && e < N_NODES) {  // poison-safe (0xAA.. is negative)
    int len = e - s + 1;
    int cs = s + (int)(((long long)len * c) / POOL_CHUNKS);
    int ce = s + (int)(((long long)len * (c + 1)) / POOL_CHUNKS);
    for (int i = cs; i < ce; ++i) m = fmaxf(m, h2f(H[(size_t)i * LDH + t]));
  }
  part[(size_t)(g * POOL_CHUNKS + c) * DOUT + t] = m;
}

__global__ void k_poolcls(const float* __restrict__ part, const float* __restrict__ Wcls,
                          const float* __restrict__ bcls, float* __restrict__ out) {
  __shared__ float l0s[256], l1s[256];
  int g = blockIdx.x, t = threadIdx.x;
  float c0 = 0.f, c1 = 0.f;
  if (t < DOUT) {
    float m = -3.4e38f;
    #pragma unroll
    for (int c = 0; c < POOL_CHUNKS; ++c)
      m = fmaxf(m, part[(size_t)(g * POOL_CHUNKS + c) * DOUT + t]);
    c0 = m * Wcls[t * 2 + 0];
    c1 = m * Wcls[t * 2 + 1];
  }
  l0s[t] = c0; l1s[t] = c1;
  __syncthreads();
  for (int o = 128; o > 0; o >>= 1) {
    if (t < o) { l0s[t] += l0s[t + o]; l1s[t] += l1s[t + o]; }
    __syncthreads();
  }
  if (t == 0) {
    float l0 = l0s[0] + bcls[0], l1 = l1s[0] + bcls[1];
    float m = fmaxf(l0, l1);
    float e0 = expf(l0 - m), e1 = expf(l1 - m);
    float inv = 1.0f / (e0 + e1);
    out[g * 2 + 0] = e0 * inv;
    out[g * 2 + 1] = e1 * inv;
  }
}

static inline size_t align256(size_t x) { return (x + 255) & ~(size_t)255; }

extern "C" void kernel_launch(void* const* d_in, const int* in_sizes, int n_in,
                              void* d_out, int out_size, void* d_ws, size_t ws_size,
                              hipStream_t stream) {
  const float* x     = (const float*)d_in[0];
  const int*   ei    = (const int*)d_in[1];
  const int*   batch = (const int*)d_in[2];
  const float* W1    = (const float*)d_in[3];
  const float* b1    = (const float*)d_in[4];
  const float* Wc    = (const float*)d_in[5];
  const float* bc    = (const float*)d_in[6];
  const float* W2    = (const float*)d_in[7];
  const float* b2    = (const float*)d_in[8];
  const float* W3    = (const float*)d_in[9];
  const float* b3    = (const float*)d_in[10];
  const float* Wcls  = (const float*)d_in[11];
  const float* bcls  = (const float*)d_in[12];
  float* out = (float*)d_out;

  const int N = N_NODES, E = N_EDGES;
  const int* src = ei;
  const int* dst = ei + E;

  char* ws = (char*)d_ws;
  size_t off = 0;
  float* dinv   = (float*)(ws + off); off = align256(off + (size_t)N * 4);
  int*   rowptr = (int*)  (ws + off); off = align256(off + (size_t)(N + 1) * 4);
  int*   col    = (int*)  (ws + off); off = align256(off + (size_t)E * 4);
  int*   gcur   = (int*)  (ws + off); off = align256(off + (size_t)NB * 4);
  int*   gstart = (int*)  (ws + off); off = align256(off + 512);
  int*   gend   = (int*)  (ws + off); off = align256(off + 512);
  float* Wc2    = (float*)(ws + off); off = align256(off + (size_t)DOUT * DOUT * 4);
  float* bc2    = (float*)(ws + off); off = align256(off + (size_t)DOUT * 4);
  u16*   Wpk1   = (u16*)  (ws + off); off = align256(off + (size_t)4 * 13 * 64 * 8 * 2);
  u16*   Wpk2   = (u16*)  (ws + off); off = align256(off + (size_t)7 * 13 * 64 * 8 * 2);
  u16*   Wpk3   = (u16*)  (ws + off); off = align256(off + (size_t)7 * 13 * 64 * 8 * 2);
  u16*   xs     = (u16*)  (ws + off); off = align256(off + ((size_t)N * LDX + 128) * 2);
  u16*   bufX   = (u16*)  (ws + off); off = align256(off + ((size_t)N * LDX + 128) * 2);
  u16*   buf0   = (u16*)  (ws + off); off = align256(off + ((size_t)N * LDH + 128) * 2);
  u16*   buf1   = (u16*)  (ws + off); off = align256(off + ((size_t)N * LDH + 128) * 2);
  u16*   buf2   = (u16*)  (ws + off); off = align256(off + ((size_t)N * LDH + 128) * 2);

  uint2* ebuf = (uint2*)buf0;   // 16.0 MB bucket scratch aliases buf0 (dead before GEMM1 out)
  float* part = (float*)buf1;   // pooling partials alias buf1 (dead at pool time)

  // 1) prep: graph bounds, Wc@W2 fold, pack W1/W3, init cursors
  k_prep<<<B_TOT, 256, 0, stream>>>(batch, gstart, gend, gcur,
                                    Wc, bc, W2, Wc2, bc2, W1, W3, Wpk1, Wpk3);
  // 2) bucketize edges by dst (391 buckets of 256 nodes)
  k_bucket<<<(E + EPB - 1) / EPB, 256, 0, stream>>>(src, dst, gcur, ebuf, E);
  // 3) per-bucket CSR build -> rowptr, dinv, col
  k_csr<<<NB, 256, 0, stream>>>(ebuf, gcur, rowptr, dinv, col);
  // 4) post: xs = dinv*x (f16 @LDX) + pack Wc2
  k_post<<<P_TOT, 256, 0, stream>>>(x, dinv, xs, Wc2, Wpk2);

  int gemmb = (N + 127) / 128;
  int aggb  = (N + 3) / 4;

  // layer 1: agg(xs) -> GEMM W1 (+b1, relu), unscaled H1
  k_agg100h<<<aggb, 256, 0, stream>>>(xs, dinv, rowptr, col, bufX);
  k_gemm_mfma<4><<<gemmb, 256, 0, stream>>>(bufX, LDX, Wpk1, b1, nullptr, buf0, 1, N);
  // T2s = dinv .* (H1 @ (Wc@W2) + bc@W2)
  k_gemm_mfma<7><<<gemmb, 256, 0, stream>>>(buf0, LDH, Wpk2, bc2, dinv, buf2, 0, N);
  // h2 = relu(di*(sum T2s + T2s_self) + b2)
  k_agg200h<<<aggb, 256, 0, stream>>>(buf2, dinv, rowptr, col, b2, buf0, 1);
  // T3s = dinv .* (h2 @ W3)
  k_gemm_mfma<7><<<gemmb, 256, 0, stream>>>(buf0, LDH, Wpk3, nullptr, dinv, buf1, 0, N);
  // h3 = di*(sum T3s + T3s_self) + b3
  k_agg200h<<<aggb, 256, 0, stream>>>(buf1, dinv, rowptr, col, b3, buf2, 0);

  // pool + fused classifier/softmax
  dim3 pg(N_GRAPHS, POOL_CHUNKS);
  k_pool1h<<<pg, 256, 0, stream>>>(buf2, gstart, gend, part);
  k_poolcls<<<N_GRAPHS, 256, 0, stream>>>(part, Wcls, bcls, out);
}

// Round 13
// 679.514 us; speedup vs baseline: 1.2072x; 1.0016x over previous
//
#include <hip/hip_runtime.h>
#include <stdint.h>

#define N_NODES 100000
#define N_EDGES 1600000
#define N_GRAPHS 128
#define DIN 100
#define DOUT 200
#define LDH 200   // f16 row stride for 200-dim buffers (400 B)
#define LDX 128   // f16 row stride for 100-dim layer (256 B = 4 lines, aligned)

#define NB 391       // buckets of 256 nodes (391*256 >= 100000)
#define BCAP 5120    // per-bucket capacity; E/NB=4092, sigma~64 -> +16 sigma margin
#define EPB 2048     // edges per block in bucketize
#define NBLK 782     // ceil(E / EPB)

typedef unsigned short u16;
typedef unsigned int u32;
typedef _Float16 f16;
typedef f16 half8 __attribute__((ext_vector_type(8)));
typedef f16 half4 __attribute__((ext_vector_type(4)));
typedef f16 half2v __attribute__((ext_vector_type(2)));
typedef float floatx4 __attribute__((ext_vector_type(4)));

__device__ __forceinline__ float h2f(u16 h) {
  f16 x; __builtin_memcpy(&x, &h, 2); return (float)x;
}
__device__ __forceinline__ u16 f2h(float f) {
  f16 x = (f16)f; u16 r; __builtin_memcpy(&r, &x, 2); return r;
}

// ---------- pack W[K,200] (fp32) into MFMA B-frag order ----------
// frag(ks, ct, lane, j) = f16( W[k][n] ), n = ct*16 + (lane&15), k = ks*32 + (lane>>4)*8 + j
__device__ __forceinline__ void pack_frag(const float* __restrict__ W, int K, int nfrag,
                                          u16* __restrict__ out, int idx) {
  if (idx >= nfrag) return;
  int lane = idx & 63;
  int t = idx >> 6;
  int ct = t % 13, ks = t / 13;
  int n = ct * 16 + (lane & 15);
  int kbase = ks * 32 + (lane >> 4) * 8;
  u16 v[8];
  #pragma unroll
  for (int j = 0; j < 8; ++j) {
    int k = kbase + j;
    float f = (k < K && n < DOUT) ? W[(size_t)k * DOUT + n] : 0.f;
    v[j] = f2h(f);
  }
  uint4 o;
  o.x = (u32)v[0] | ((u32)v[1] << 16);
  o.y = (u32)v[2] | ((u32)v[3] << 16);
  o.z = (u32)v[4] | ((u32)v[5] << 16);
  o.w = (u32)v[6] | ((u32)v[7] << 16);
  *(uint4*)(out + (size_t)idx * 8) = o;
}

// ---------- fused prep: gbound | comb | pack1 | pack3 | edge-histogram ----------
// (no gstart/gend sentinel init — racing with gbound band caused r9 NaN; poison guard covers)
// hist band: per-block LDS histogram of 2048 edges -> histAll[blk][bucket], NO global atomics
#define B_GB    391
#define B_COMB  549
#define B_PK1   562
#define B_PK3   585
#define B_TOT   (585 + NBLK)
__global__ void k_prep(const int* __restrict__ batch, int* __restrict__ gstart,
                       int* __restrict__ gend, const int* __restrict__ dst,
                       int* __restrict__ histAll,
                       const float* __restrict__ Wc, const float* __restrict__ bc,
                       const float* __restrict__ W2, float* __restrict__ Wc2,
                       float* __restrict__ bc2, const float* __restrict__ W1,
                       const float* __restrict__ W3, u16* __restrict__ Wpk1,
                       u16* __restrict__ Wpk3) {
  int b = blockIdx.x, t = threadIdx.x;
  if (b < B_GB) {
    int i = b * 256 + t;
    if (i >= N_NODES) return;
    int g = batch[i];
    if (i == 0 || batch[i - 1] != g) gstart[g] = i;
    if (i == N_NODES - 1 || batch[i + 1] != g) gend[g] = i;
  } else if (b < B_COMB) {
    int gid = (b - B_GB) * 256 + t;
    if (gid >= 201 * DOUT) return;
    int r = gid / DOUT, c = gid % DOUT;
    const float* a = (r < DOUT) ? (Wc + (size_t)r * DOUT) : bc;
    float s = 0.f;
    for (int k = 0; k < DOUT; ++k) s += a[k] * W2[(size_t)k * DOUT + c];
    if (r < DOUT) Wc2[(size_t)r * DOUT + c] = s;
    else bc2[c] = s;
  } else if (b < B_PK1) {
    pack_frag(W1, DIN, 4 * 13 * 64, Wpk1, (b - B_COMB) * 256 + t);
  } else if (b < B_PK3) {
    pack_frag(W3, DOUT, 7 * 13 * 64, Wpk3, (b - B_PK1) * 256 + t);
  } else {
    __shared__ int hist[NB];
    int hb = b - B_PK3;
    int e0 = hb * EPB;
    int e1 = min(e0 + EPB, N_EDGES);
    for (int j = t; j < NB; j += 256) hist[j] = 0;
    __syncthreads();
    for (int i = e0 + t; i < e1; i += 256)
      atomicAdd(&hist[dst[i] >> 8], 1);
    __syncthreads();
    for (int j = t; j < NB; j += 256)
      histAll[(size_t)hb * NB + j] = hist[j];
  }
}

// ---------- per-bucket prefix over blocks: baseAll[blk][bucket], totals -> gcur ----------
__global__ void k_scan(const int* __restrict__ histAll, int* __restrict__ baseAll,
                       int* __restrict__ gcur) {
  __shared__ int s[256];
  int j = blockIdx.x, t = threadIdx.x;
  int run = 0;
  for (int c = 0; c < NBLK; c += 256) {
    int idx = c + t;
    int v = (idx < NBLK) ? histAll[(size_t)idx * NB + j] : 0;
    s[t] = v;
    __syncthreads();
    for (int o = 1; o < 256; o <<= 1) {
      int x = (t >= o) ? s[t - o] : 0;
      __syncthreads();
      s[t] += x;
      __syncthreads();
    }
    if (idx < NBLK) baseAll[(size_t)idx * NB + j] = run + s[t] - v;
    run += s[255];
    __syncthreads();
  }
  if (t == 0) gcur[j] = run;
}

// ---------- scatter edges to ebuf at precomputed positions (LDS cursors only) ----------
__global__ void k_scatter(const int* __restrict__ src, const int* __restrict__ dst,
                          const int* __restrict__ baseAll, uint2* __restrict__ ebuf) {
  __shared__ int cur[NB];
  int b = blockIdx.x, t = threadIdx.x;
  int e0 = b * EPB;
  int e1 = min(e0 + EPB, N_EDGES);
  for (int j = t; j < NB; j += 256) cur[j] = baseAll[(size_t)b * NB + j];
  __syncthreads();
  for (int i = e0 + t; i < e1; i += 256) {
    int d = dst[i];
    int bk = d >> 8;
    int pos = atomicAdd(&cur[bk], 1);
    if (pos < BCAP)
      ebuf[(size_t)bk * BCAP + pos] = make_uint2((u32)d, (u32)src[i]);
  }
}

// ---------- per-bucket (256 nodes) count+scan -> rowptr,dinv ; scatter -> col ----------
__global__ void k_csr(const uint2* __restrict__ ebuf, const int* __restrict__ gcur,
                      int* __restrict__ rowptr, float* __restrict__ dinv,
                      int* __restrict__ colv) {
  __shared__ int s_cnt[256];
  __shared__ int s_cur[256];
  __shared__ int s_scan[256];
  __shared__ int s_g[NB];
  __shared__ int s_base;
  int b = blockIdx.x, t = threadIdx.x;
  for (int j = t; j < NB; j += 256) s_g[j] = gcur[j];
  s_cnt[t] = 0;
  __syncthreads();
  if (t == 0) {
    int run = 0;
    for (int i = 0; i < b; ++i) run += s_g[i];
    s_base = run;
    if (b == NB - 1) rowptr[N_NODES] = run + s_g[b];  // == E
  }
  __syncthreads();
  int cnt = s_g[b];
  int base = s_base;
  int node0 = b << 8;
  const uint2* eb = ebuf + (size_t)b * BCAP;
  for (int i = t; i < cnt; i += 256)
    atomicAdd(&s_cnt[eb[i].x & 255], 1);
  __syncthreads();
  int v = s_cnt[t];
  s_scan[t] = v;
  __syncthreads();
  for (int o = 1; o < 256; o <<= 1) {
    int x = (t >= o) ? s_scan[t - o] : 0;
    __syncthreads();
    s_scan[t] += x;
    __syncthreads();
  }
  int run = s_scan[t] - v;  // exclusive
  s_cur[t] = base + run;
  int node = node0 + t;
  if (node < N_NODES) {
    rowptr[node] = base + run;
    dinv[node] = rsqrtf((float)v + 1.0f);
  }
  __syncthreads();
  for (int i = t; i < cnt; i += 256) {
    uint2 e = eb[i];
    int pos = atomicAdd(&s_cur[e.x & 255], 1);
    colv[pos] = (int)e.y;
  }
}

// ---------- fused post: xs = dinv * x -> f16 @LDX | pack2 ----------
#define P_XS  25000
#define P_TOT 25023
__global__ void k_post(const float* __restrict__ x, const float* __restrict__ dinv,
                       u16* __restrict__ xs, const float* __restrict__ Wc2,
                       u16* __restrict__ Wpk2) {
  int b = blockIdx.x, t = threadIdx.x;
  if (b < P_XS) {
    int gid = b * 256 + t;
    int node = gid >> 6, lane = gid & 63;
    if (node >= N_NODES) return;
    if (lane >= 50) {  // zero cols 100..127 (14 lanes x 2)
      int c = 100 + (lane - 50) * 2;
      *(half2v*)(xs + (size_t)node * LDX + c) = half2v{0, 0};
      return;
    }
    float d = dinv[node];
    float2 vv = *(const float2*)(x + (size_t)node * DIN + lane * 2);
    half2v o; o[0] = (f16)(d * vv.x); o[1] = (f16)(d * vv.y);
    *(half2v*)(xs + (size_t)node * LDX + lane * 2) = o;
  } else {
    pack_frag(Wc2, DOUT, 7 * 13 * 64, Wpk2, (b - P_XS) * 256 + t);
  }
}

// ---------- MFMA GEMM: C = A @ Wpk (+bias)(+relu)(row-scale by dinv), 32 rows/wave ----------
template <int NKS>
__global__ __launch_bounds__(256) void k_gemm_mfma(const u16* __restrict__ A, int lda,
                                                   const u16* __restrict__ Wpk,
                                                   const float* __restrict__ bias,
                                                   const float* __restrict__ rowscale,
                                                   u16* __restrict__ C, int relu, int nrows) {
  int wv = threadIdx.x >> 6;
  int lane = threadIdx.x & 63;
  int r0 = blockIdx.x * 128 + wv * 32;
  int m = lane & 15, q = lane >> 4;
  int row0 = r0 + m, row1 = r0 + 16 + m;
  bool ok0 = (row0 < nrows), ok1 = (row1 < nrows);
  const u16* a0p = A + (size_t)row0 * lda + q * 8;
  const u16* a1p = A + (size_t)row1 * lda + q * 8;

  floatx4 acc0[13], acc1[13];
  #pragma unroll
  for (int ct = 0; ct < 13; ++ct) {
    acc0[ct] = floatx4{0.f, 0.f, 0.f, 0.f};
    acc1[ct] = floatx4{0.f, 0.f, 0.f, 0.f};
  }

  const u16* wp = Wpk + (size_t)lane * 8;
  #pragma unroll
  for (int ks = 0; ks < NKS; ++ks) {
    half8 a0 = ok0 ? *(const half8*)(a0p + ks * 32) : half8{0, 0, 0, 0, 0, 0, 0, 0};
    half8 a1 = ok1 ? *(const half8*)(a1p + ks * 32) : half8{0, 0, 0, 0, 0, 0, 0, 0};
    #pragma unroll
    for (int ct = 0; ct < 13; ++ct) {
      half8 bfr = *(const half8*)(wp + (size_t)(ks * 13 + ct) * 512);
      acc0[ct] = __builtin_amdgcn_mfma_f32_16x16x32_f16(a0, bfr, acc0[ct], 0, 0, 0);
      acc1[ct] = __builtin_amdgcn_mfma_f32_16x16x32_f16(a1, bfr, acc1[ct], 0, 0, 0);
    }
  }

  float sc0[4], sc1[4];
  #pragma unroll
  for (int rg = 0; rg < 4; ++rg) {
    int or0 = r0 + q * 4 + rg;
    int or1 = r0 + 16 + q * 4 + rg;
    sc0[rg] = (rowscale && or0 < nrows) ? rowscale[or0] : 1.f;
    sc1[rg] = (rowscale && or1 < nrows) ? rowscale[or1] : 1.f;
  }

  // C/D layout: col = ct*16 + m, row = base + q*4 + reg
  #pragma unroll
  for (int ct = 0; ct < 13; ++ct) {
    int c = ct * 16 + m;
    if (c >= DOUT) continue;
    float bv = bias ? bias[c] : 0.f;
    #pragma unroll
    for (int rg = 0; rg < 4; ++rg) {
      int or0 = r0 + q * 4 + rg;
      if (or0 < nrows) {
        float v = acc0[ct][rg] + bv;
        if (relu) v = fmaxf(v, 0.f);
        C[(size_t)or0 * LDH + c] = f2h(v * sc0[rg]);
      }
      int or1 = r0 + 16 + q * 4 + rg;
      if (or1 < nrows) {
        float v = acc1[ct][rg] + bv;
        if (relu) v = fmaxf(v, 0.f);
        C[(size_t)or1 * LDH + c] = f2h(v * sc1[rg]);
      }
    }
  }
}

// ---------- aggregation D=200, pre-scaled rows: out = relu?(di*(sum Ts[col] + Ts[i]) + b) ----------
__global__ void k_agg200h(const u16* __restrict__ T, const float* __restrict__ dinv,
                          const int* __restrict__ rowptr, const int* __restrict__ col,
                          const float* __restrict__ bias, u16* __restrict__ OUT,
                          int relu) {
  int wave = (blockIdx.x * blockDim.x + threadIdx.x) >> 6;
  int lane = threadIdx.x & 63;
  if (wave >= N_NODES || lane >= 50) return;
  int node = wave;
  int c4 = lane * 4;
  float ax = 0.f, ay = 0.f, az = 0.f, aw = 0.f;
  int beg = rowptr[node], end = rowptr[node + 1];
  int e = beg;
  for (; e + 8 <= end; e += 8) {
    int s[8];
    half4 tv[8];
    #pragma unroll
    for (int j = 0; j < 8; ++j) s[j] = col[e + j];
    #pragma unroll
    for (int j = 0; j < 8; ++j)
      tv[j] = *(const half4*)(T + (size_t)s[j] * LDH + c4);
    #pragma unroll
    for (int j = 0; j < 8; ++j) {
      ax += (float)tv[j][0];
      ay += (float)tv[j][1];
      az += (float)tv[j][2];
      aw += (float)tv[j][3];
    }
  }
  for (; e < end; ++e) {
    half4 tv = *(const half4*)(T + (size_t)col[e] * LDH + c4);
    ax += (float)tv[0]; ay += (float)tv[1];
    az += (float)tv[2]; aw += (float)tv[3];
  }
  float di = dinv[node];
  half4 sv = *(const half4*)(T + (size_t)node * LDH + c4);
  float rx = di * (ax + (float)sv[0]);
  float ry = di * (ay + (float)sv[1]);
  float rz = di * (az + (float)sv[2]);
  float rw = di * (aw + (float)sv[3]);
  if (bias) {
    rx += bias[c4 + 0]; ry += bias[c4 + 1];
    rz += bias[c4 + 2]; rw += bias[c4 + 3];
  }
  if (relu) {
    rx = fmaxf(rx, 0.f); ry = fmaxf(ry, 0.f);
    rz = fmaxf(rz, 0.f); rw = fmaxf(rw, 0.f);
  }
  half4 o;
  o[0] = (f16)rx; o[1] = (f16)ry; o[2] = (f16)rz; o[3] = (f16)rw;
  *(half4*)(OUT + (size_t)node * LDH + c4) = o;
}

// ---------- aggregation D=100 on pre-scaled xs (LDX aligned), out @LDX ----------
__global__ void k_agg100h(const u16* __restrict__ T, const float* __restrict__ dinv,
                          const int* __restrict__ rowptr, const int* __restrict__ col,
                          u16* __restrict__ OUT) {
  int wave = (blockIdx.x * blockDim.x + threadIdx.x) >> 6;
  int lane = threadIdx.x & 63;
  if (wave >= N_NODES) return;
  int node = wave;
  if (lane >= 50) {
    int c = 100 + (lane - 50) * 2;
    *(half2v*)(OUT + (size_t)node * LDX + c) = half2v{0, 0};
    return;
  }
  int c2 = lane * 2;
  float ax = 0.f, ay = 0.f;
  int beg = rowptr[node], end = rowptr[node + 1];
  int e = beg;
  for (; e + 8 <= end; e += 8) {
    int s[8];
    half2v tv[8];
    #pragma unroll
    for (int j = 0; j < 8; ++j) s[j] = col[e + j];
    #pragma unroll
    for (int j = 0; j < 8; ++j)
      tv[j] = *(const half2v*)(T + (size_t)s[j] * LDX + c2);
    #pragma unroll
    for (int j = 0; j < 8; ++j) {
      ax += (float)tv[j][0];
      ay += (float)tv[j][1];
    }
  }
  for (; e < end; ++e) {
    half2v tv = *(const half2v*)(T + (size_t)col[e] * LDX + c2);
    ax += (float)tv[0]; ay += (float)tv[1];
  }
  float di = dinv[node];
  half2v sv = *(const half2v*)(T + (size_t)node * LDX + c2);
  half2v o;
  o[0] = (f16)(di * (ax + (float)sv[0]));
  o[1] = (f16)(di * (ay + (float)sv[1]));
  *(half2v*)(OUT + (size_t)node * LDX + c2) = o;
}

// ---------- pooling ----------
#define POOL_CHUNKS 8
__global__ void k_pool1h(const u16* __restrict__ H, const int* __restrict__ gstart,
                         const int* __restrict__ gend, float* __restrict__ part) {
  int g = blockIdx.x, c = blockIdx.y, t = threadIdx.x;
  if (t >= DOUT) return;
  int s = gstart[g], e = gend[g];
  float m = -3.4e38f;
  if (s >= 0 && e >= s && e < N_NODES) {  // poison-safe (0xAA.. is negative)
    int len = e - s + 1;
    int cs = s + (int)(((long long)len * c) / POOL_CHUNKS);
    int ce = s + (int)(((long long)len * (c + 1)) / POOL_CHUNKS);
    for (int i = cs; i < ce; ++i) m = fmaxf(m, h2f(H[(size_t)i * LDH + t]));
  }
  part[(size_t)(g * POOL_CHUNKS + c) * DOUT + t] = m;
}

__global__ void k_poolcls(const float* __restrict__ part, const float* __restrict__ Wcls,
                          const float* __restrict__ bcls, float* __restrict__ out) {
  __shared__ float l0s[256], l1s[256];
  int g = blockIdx.x, t = threadIdx.x;
  float c0 = 0.f, c1 = 0.f;
  if (t < DOUT) {
    float m = -3.4e38f;
    #pragma unroll
    for (int c = 0; c < POOL_CHUNKS; ++c)
      m = fmaxf(m, part[(size_t)(g * POOL_CHUNKS + c) * DOUT + t]);
    c0 = m * Wcls[t * 2 + 0];
    c1 = m * Wcls[t * 2 + 1];
  }
  l0s[t] = c0; l1s[t] = c1;
  __syncthreads();
  for (int o = 128; o > 0; o >>= 1) {
    if (t < o) { l0s[t] += l0s[t + o]; l1s[t] += l1s[t + o]; }
    __syncthreads();
  }
  if (t == 0) {
    float l0 = l0s[0] + bcls[0], l1 = l1s[0] + bcls[1];
    float m = fmaxf(l0, l1);
    float e0 = expf(l0 - m), e1 = expf(l1 - m);
    float inv = 1.0f / (e0 + e1);
    out[g * 2 + 0] = e0 * inv;
    out[g * 2 + 1] = e1 * inv;
  }
}

static inline size_t align256(size_t x) { return (x + 255) & ~(size_t)255; }

extern "C" void kernel_launch(void* const* d_in, const int* in_sizes, int n_in,
                              void* d_out, int out_size, void* d_ws, size_t ws_size,
                              hipStream_t stream) {
  const float* x     = (const float*)d_in[0];
  const int*   ei    = (const int*)d_in[1];
  const int*   batch = (const int*)d_in[2];
  const float* W1    = (const float*)d_in[3];
  const float* b1    = (const float*)d_in[4];
  const float* Wc    = (const float*)d_in[5];
  const float* bc    = (const float*)d_in[6];
  const float* W2    = (const float*)d_in[7];
  const float* b2    = (const float*)d_in[8];
  const float* W3    = (const float*)d_in[9];
  const float* b3    = (const float*)d_in[10];
  const float* Wcls  = (const float*)d_in[11];
  const float* bcls  = (const float*)d_in[12];
  float* out = (float*)d_out;

  const int N = N_NODES, E = N_EDGES;
  const int* src = ei;
  const int* dst = ei + E;

  char* ws = (char*)d_ws;
  size_t off = 0;
  float* dinv    = (float*)(ws + off); off = align256(off + (size_t)N * 4);
  int*   rowptr  = (int*)  (ws + off); off = align256(off + (size_t)(N + 1) * 4);
  int*   col     = (int*)  (ws + off); off = align256(off + (size_t)E * 4);
  int*   gcur    = (int*)  (ws + off); off = align256(off + (size_t)NB * 4);
  int*   histAll = (int*)  (ws + off); off = align256(off + (size_t)NBLK * NB * 4);
  int*   baseAll = (int*)  (ws + off); off = align256(off + (size_t)NBLK * NB * 4);
  int*   gstart  = (int*)  (ws + off); off = align256(off + 512);
  int*   gend    = (int*)  (ws + off); off = align256(off + 512);
  float* Wc2     = (float*)(ws + off); off = align256(off + (size_t)DOUT * DOUT * 4);
  float* bc2     = (float*)(ws + off); off = align256(off + (size_t)DOUT * 4);
  u16*   Wpk1    = (u16*)  (ws + off); off = align256(off + (size_t)4 * 13 * 64 * 8 * 2);
  u16*   Wpk2    = (u16*)  (ws + off); off = align256(off + (size_t)7 * 13 * 64 * 8 * 2);
  u16*   Wpk3    = (u16*)  (ws + off); off = align256(off + (size_t)7 * 13 * 64 * 8 * 2);
  u16*   xs      = (u16*)  (ws + off); off = align256(off + ((size_t)N * LDX + 128) * 2);
  u16*   bufX    = (u16*)  (ws + off); off = align256(off + ((size_t)N * LDX + 128) * 2);
  u16*   buf0    = (u16*)  (ws + off); off = align256(off + ((size_t)N * LDH + 128) * 2);
  u16*   buf1    = (u16*)  (ws + off); off = align256(off + ((size_t)N * LDH + 128) * 2);
  u16*   buf2    = (u16*)  (ws + off); off = align256(off + ((size_t)N * LDH + 128) * 2);

  uint2* ebuf = (uint2*)buf0;   // 16.0 MB bucket scratch aliases buf0 (dead before GEMM1 out)
  float* part = (float*)buf1;   // pooling partials alias buf1 (dead at pool time)

  // 1) prep: graph bounds, Wc@W2 fold, pack W1/W3, per-block edge histograms
  k_prep<<<B_TOT, 256, 0, stream>>>(batch, gstart, gend, dst, histAll,
                                    Wc, bc, W2, Wc2, bc2, W1, W3, Wpk1, Wpk3);
  // 2) per-bucket prefix over blocks (deterministic bases; no global atomics)
  k_scan<<<NB, 256, 0, stream>>>(histAll, baseAll, gcur);
  // 3) scatter edges into bucket order at exact positions
  k_scatter<<<NBLK, 256, 0, stream>>>(src, dst, baseAll, ebuf);
  // 4) per-bucket CSR build -> rowptr, dinv, col
  k_csr<<<NB, 256, 0, stream>>>(ebuf, gcur, rowptr, dinv, col);
  // 5) post: xs = dinv*x (f16 @LDX) + pack Wc2
  k_post<<<P_TOT, 256, 0, stream>>>(x, dinv, xs, Wc2, Wpk2);

  int gemmb = (N + 127) / 128;
  int aggb  = (N + 3) / 4;

  // layer 1: agg(xs) -> GEMM W1 (+b1, relu), unscaled H1
  k_agg100h<<<aggb, 256, 0, stream>>>(xs, dinv, rowptr, col, bufX);
  k_gemm_mfma<4><<<gemmb, 256, 0, stream>>>(bufX, LDX, Wpk1, b1, nullptr, buf0, 1, N);
  // T2s = dinv .* (H1 @ (Wc@W2) + bc@W2)
  k_gemm_mfma<7><<<gemmb, 256, 0, stream>>>(buf0, LDH, Wpk2, bc2, dinv, buf2, 0, N);
  // h2 = relu(di*(sum T2s + T2s_self) + b2)
  k_agg200h<<<aggb, 256, 0, stream>>>(buf2, dinv, rowptr, col, b2, buf0, 1);
  // T3s = dinv .* (h2 @ W3)
  k_gemm_mfma<7><<<gemmb, 256, 0, stream>>>(buf0, LDH, Wpk3, nullptr, dinv, buf1, 0, N);
  // h3 = di*(sum T3s + T3s_self) + b3
  k_agg200h<<<aggb, 256, 0, stream>>>(buf1, dinv, rowptr, col, b3, buf2, 0);

  // pool + fused classifier/softmax
  dim3 pg(N_GRAPHS, POOL_CHUNKS);
  k_pool1h<<<pg, 256, 0, stream>>>(buf2, gstart, gend, part);
  k_poolcls<<<N_GRAPHS, 256, 0, stream>>>(part, Wcls, bcls, out);
}